// Round 4
// baseline (905.710 us; speedup 1.0000x reference)
//
#include <hip/hip_runtime.h>
#include <hip/hip_bf16.h>
#include <math.h>

#define BATCH 8192
#define HID   4096
#define KDIM  512
#define OUT   1024

#define BM 128
#define BN 128
#define BK 32
#define NKSTEP (KDIM / BK)   // 16
#define NCH 64               // HID / 64 partial chunks per row

typedef __attribute__((ext_vector_type(8))) short bf16x8;
typedef __attribute__((ext_vector_type(4))) float f32x4;

__device__ __forceinline__ ushort bf16_rne(float x) {
  unsigned u = __float_as_uint(x);
  unsigned r = u + 0x7fffu + ((u >> 16) & 1u);
  return (ushort)(r >> 16);
}

__device__ __forceinline__ void top2_upd(float v, int idx, float& v1, int& i1,
                                         float& v2, int& i2) {
  if (v < v1 || (v == v1 && idx < i1)) { v2 = v1; i2 = i1; v1 = v; i1 = idx; }
  else if (v < v2 || (v == v2 && idx < i2)) { v2 = v; i2 = idx; }
}

__device__ __forceinline__ void top3_upd(float v, int idx,
    float& v1, int& i1, float& v2, int& i2, float& v3, int& i3) {
  if (v < v1 || (v == v1 && idx < i1)) { v3 = v2; i3 = i2; v2 = v1; i2 = i1; v1 = v; i1 = idx; }
  else if (v < v2 || (v == v2 && idx < i2)) { v3 = v2; i3 = i2; v2 = v; i2 = idx; }
  else if (v < v3 || (v == v3 && idx < i3)) { v3 = v; i3 = idx; }
}

// ---- split f32 -> bf16 hi + bf16 lo (x = hi + lo + O(2^-17 x)) --------------
__global__ void __launch_bounds__(256)
split_kernel(const float* __restrict__ src, ushort* __restrict__ hi,
             ushort* __restrict__ lo, int n4) {
  int i = blockIdx.x * 256 + threadIdx.x;
  if (i >= n4) return;
  float4 v = ((const float4*)src)[i];
  ushort4 h, l;
  float f;
  h.x = bf16_rne(v.x); f = __uint_as_float((unsigned)h.x << 16); l.x = bf16_rne(v.x - f);
  h.y = bf16_rne(v.y); f = __uint_as_float((unsigned)h.y << 16); l.y = bf16_rne(v.y - f);
  h.z = bf16_rne(v.z); f = __uint_as_float((unsigned)h.z << 16); l.z = bf16_rne(v.z - f);
  h.w = bf16_rne(v.w); f = __uint_as_float((unsigned)h.w << 16); l.w = bf16_rne(v.w - f);
  ((ushort4*)hi)[i] = h;
  ((ushort4*)lo)[i] = l;
}

// ---------------- w2[j] = sum_k W[j,k]^2 (f32, approx pass only) -------------
__global__ void __launch_bounds__(64)
w2_kernel(const float* __restrict__ W, float* __restrict__ w2) {
  int j = blockIdx.x, lane = threadIdx.x;
  const float4* row = (const float4*)(W + (size_t)j * KDIM);
  float s = 0.f;
#pragma unroll
  for (int i = 0; i < 2; ++i) {
    float4 v = row[lane + i * 64];
    s += v.x * v.x + v.y * v.y + v.z * v.z + v.w * v.w;
  }
#pragma unroll
  for (int off = 32; off; off >>= 1) s += __shfl_down(s, off);
  if (lane == 0) w2[j] = s;
}

// ------ split-bf16 MFMA GEMM (dot = XhWh + XlWh + XhWl) + fused top-2 --------
// 128x128 tile, 4 waves (2x2), 64x64 per wave, 16x16x32 MFMA, BK=32.
// LDS layout per tile: unit u = kb*128 + row (16B = 8 bf16 of k), so frag reads
// (lane lr=row, lg=kb) are lane-sequential 16B -> conflict-free.
__global__ void __launch_bounds__(256)
mfma_dist_kernel(const ushort* __restrict__ xh, const ushort* __restrict__ xl,
                 const ushort* __restrict__ wh, const ushort* __restrict__ wl,
                 const float* __restrict__ w2, float4* __restrict__ partials) {
  __shared__ ushort xh_s[4 * 128 * 8];
  __shared__ ushort xl_s[4 * 128 * 8];
  __shared__ ushort wh_s[4 * 128 * 8];
  __shared__ ushort wl_s[4 * 128 * 8];

  const int tid = threadIdx.x;
  // bijective XCD swizzle (nwg=2048, 2048%8==0)
  const int wg = (int)blockIdx.x;
  const int swz = (wg & 7) * 256 + (wg >> 3);
  const int rb = swz >> 5;            // 64 row-blocks
  const int cb = swz & 31;            // 32 col-blocks
  const int row0 = rb * BM;
  const int col0 = cb * BN;

  // staging: thread t loads k-block skb = t&3, rows sr and sr+64
  const int skb = tid & 3;
  const int sr = tid >> 2;
  const size_t gx0 = (size_t)(row0 + sr) * KDIM + skb * 8;
  const size_t gx1 = (size_t)(row0 + sr + 64) * KDIM + skb * 8;
  const size_t gw0 = (size_t)(col0 + sr) * KDIM + skb * 8;
  const size_t gw1 = (size_t)(col0 + sr + 64) * KDIM + skb * 8;
  const int su0 = (skb * 128 + sr) * 8;
  const int su1 = (skb * 128 + sr + 64) * 8;

  const int lane = tid & 63;
  const int wid = tid >> 6;
  const int wr = wid >> 1, wc = wid & 1;
  const int lr = lane & 15, lg = lane >> 4;

  f32x4 acc[4][4];
#pragma unroll
  for (int mi = 0; mi < 4; ++mi)
#pragma unroll
    for (int ni = 0; ni < 4; ++ni) acc[mi][ni] = (f32x4){0.f, 0.f, 0.f, 0.f};

  uint4 rxh0, rxh1, rxl0, rxl1, rwh0, rwh1, rwl0, rwl1;
  rxh0 = *(const uint4*)(xh + gx0); rxh1 = *(const uint4*)(xh + gx1);
  rxl0 = *(const uint4*)(xl + gx0); rxl1 = *(const uint4*)(xl + gx1);
  rwh0 = *(const uint4*)(wh + gw0); rwh1 = *(const uint4*)(wh + gw1);
  rwl0 = *(const uint4*)(wl + gw0); rwl1 = *(const uint4*)(wl + gw1);

  for (int step = 0; step < NKSTEP; ++step) {
    __syncthreads();   // previous iteration's frag readers done
    *(uint4*)&xh_s[su0] = rxh0; *(uint4*)&xh_s[su1] = rxh1;
    *(uint4*)&xl_s[su0] = rxl0; *(uint4*)&xl_s[su1] = rxl1;
    *(uint4*)&wh_s[su0] = rwh0; *(uint4*)&wh_s[su1] = rwh1;
    *(uint4*)&wl_s[su0] = rwl0; *(uint4*)&wl_s[su1] = rwl1;
    __syncthreads();

    if (step + 1 < NKSTEP) {     // prefetch next K-step under the MFMA phase
      const int k1 = (step + 1) * BK;
      rxh0 = *(const uint4*)(xh + gx0 + k1); rxh1 = *(const uint4*)(xh + gx1 + k1);
      rxl0 = *(const uint4*)(xl + gx0 + k1); rxl1 = *(const uint4*)(xl + gx1 + k1);
      rwh0 = *(const uint4*)(wh + gw0 + k1); rwh1 = *(const uint4*)(wh + gw1 + k1);
      rwl0 = *(const uint4*)(wl + gw0 + k1); rwl1 = *(const uint4*)(wl + gw1 + k1);
    }

    const int abase = (lg * 128 + wr * 64 + lr) * 8;
    const int bbase = (lg * 128 + wc * 64 + lr) * 8;
    bf16x8 af[4], al[4], bfr[4];
#pragma unroll
    for (int mi = 0; mi < 4; ++mi) af[mi] = *(const bf16x8*)&xh_s[abase + mi * 128];
#pragma unroll
    for (int mi = 0; mi < 4; ++mi) al[mi] = *(const bf16x8*)&xl_s[abase + mi * 128];
#pragma unroll
    for (int ni = 0; ni < 4; ++ni) bfr[ni] = *(const bf16x8*)&wh_s[bbase + ni * 128];
#pragma unroll
    for (int mi = 0; mi < 4; ++mi)
#pragma unroll
      for (int ni = 0; ni < 4; ++ni)
        acc[mi][ni] = __builtin_amdgcn_mfma_f32_16x16x32_bf16(af[mi], bfr[ni], acc[mi][ni], 0, 0, 0);
#pragma unroll
    for (int mi = 0; mi < 4; ++mi)
#pragma unroll
      for (int ni = 0; ni < 4; ++ni)
        acc[mi][ni] = __builtin_amdgcn_mfma_f32_16x16x32_bf16(al[mi], bfr[ni], acc[mi][ni], 0, 0, 0);
#pragma unroll
    for (int ni = 0; ni < 4; ++ni) bfr[ni] = *(const bf16x8*)&wl_s[bbase + ni * 128];
#pragma unroll
    for (int mi = 0; mi < 4; ++mi)
#pragma unroll
      for (int ni = 0; ni < 4; ++ni)
        acc[mi][ni] = __builtin_amdgcn_mfma_f32_16x16x32_bf16(af[mi], bfr[ni], acc[mi][ni], 0, 0, 0);
  }

  // ---- epilogue: v = w2[col] - 2*dot ; per-row top-2 over this 64-col chunk
  float w2v[4];
#pragma unroll
  for (int ni = 0; ni < 4; ++ni) w2v[ni] = w2[col0 + wc * 64 + ni * 16 + lr];

  float v1[4][4], v2[4][4];
  int i1[4][4], i2[4][4];
#pragma unroll
  for (int mi = 0; mi < 4; ++mi)
#pragma unroll
    for (int rg = 0; rg < 4; ++rg) {
      v1[mi][rg] = 3.4e38f; v2[mi][rg] = 3.4e38f;
      i1[mi][rg] = 0x7fffffff; i2[mi][rg] = 0x7fffffff;
    }
#pragma unroll
  for (int mi = 0; mi < 4; ++mi)
#pragma unroll
    for (int ni = 0; ni < 4; ++ni) {
      const int col = col0 + wc * 64 + ni * 16 + lr;
#pragma unroll
      for (int rg = 0; rg < 4; ++rg) {
        float v = fmaf(-2.f, acc[mi][ni][rg], w2v[ni]);
        top2_upd(v, col, v1[mi][rg], i1[mi][rg], v2[mi][rg], i2[mi][rg]);
      }
    }
  // butterfly across the 16 lanes (lr) sharing each row
#pragma unroll
  for (int m = 1; m < 16; m <<= 1) {
#pragma unroll
    for (int mi = 0; mi < 4; ++mi)
#pragma unroll
      for (int rg = 0; rg < 4; ++rg) {
        float ov1 = __shfl_xor(v1[mi][rg], m);
        int oi1 = __shfl_xor(i1[mi][rg], m);
        float ov2 = __shfl_xor(v2[mi][rg], m);
        int oi2 = __shfl_xor(i2[mi][rg], m);
        top2_upd(ov1, oi1, v1[mi][rg], i1[mi][rg], v2[mi][rg], i2[mi][rg]);
        top2_upd(ov2, oi2, v1[mi][rg], i1[mi][rg], v2[mi][rg], i2[mi][rg]);
      }
  }
  if (lr == 0) {
    const int chunk = cb * 2 + wc;
#pragma unroll
    for (int mi = 0; mi < 4; ++mi)
#pragma unroll
      for (int rg = 0; rg < 4; ++rg) {
        const int row = row0 + wr * 64 + mi * 16 + lg * 4 + rg;
        partials[(size_t)row * NCH + chunk] =
            make_float4(v1[mi][rg], v2[mi][rg],
                        __int_as_float(i1[mi][rg]), __int_as_float(i2[mi][rg]));
      }
  }
}

// ------- merge 64 chunk partials; fp64 recheck top-3; emit winner ------------
__global__ void __launch_bounds__(256)
recheck_kernel(const float* __restrict__ X, const float* __restrict__ W,
               const float4* __restrict__ partials, int* __restrict__ win,
               float* __restrict__ out_idx) {
  int lane = threadIdx.x & 63;
  int b = blockIdx.x * 4 + (threadIdx.x >> 6);
  float v1 = 3.4e38f, v2 = 3.4e38f, v3 = 3.4e38f;
  int i1 = 0x7fffffff, i2 = 0x7fffffff, i3 = 0x7fffffff;
  for (int c = 0; c < NCH; ++c) {
    float4 p = partials[(size_t)b * NCH + c];
    top3_upd(p.x, __float_as_int(p.z), v1, i1, v2, i2, v3, i3);
    top3_upd(p.y, __float_as_int(p.w), v1, i1, v2, i2, v3, i3);
  }
  const float* xr = X + (size_t)b * KDIM;
  const float* w1 = W + (size_t)i1 * KDIM;
  const float* w2p = W + (size_t)i2 * KDIM;
  const float* w3 = W + (size_t)i3 * KDIM;
  double s1 = 0.0, s2 = 0.0, s3 = 0.0;
#pragma unroll
  for (int i = 0; i < KDIM / 64; ++i) {
    int k = lane + i * 64;
    double xv = (double)xr[k];
    double d1 = xv - (double)w1[k];
    double d2 = xv - (double)w2p[k];
    double d3 = xv - (double)w3[k];
    s1 += d1 * d1; s2 += d2 * d2; s3 += d3 * d3;
  }
#pragma unroll
  for (int off = 32; off; off >>= 1) {
    s1 += __shfl_down(s1, off);
    s2 += __shfl_down(s2, off);
    s3 += __shfl_down(s3, off);
  }
  if (lane == 0) {
    int wi = i1; double sb = s1;
    if (s2 < sb || (s2 == sb && i2 < wi)) { sb = s2; wi = i2; }
    if (s3 < sb || (s3 == sb && i3 < wi)) { sb = s3; wi = i3; }
    win[b] = wi;
    out_idx[b] = (float)wi;
  }
}

// --------- out0[b,:] = f32 G[:, win[b]]  (G is [OUT][HID] row-major) ---------
__global__ void __launch_bounds__(256)
gather_kernel(const float* __restrict__ G, const int* __restrict__ win,
              float* __restrict__ out0) {
  int b = blockIdx.x;
  int w = win[b];
  w = (w < 0) ? 0 : (w > HID - 1 ? HID - 1 : w);
  int o = threadIdx.x * 4;
  float4 r;
  r.x = G[(size_t)(o + 0) * HID + w];
  r.y = G[(size_t)(o + 1) * HID + w];
  r.z = G[(size_t)(o + 2) * HID + w];
  r.w = G[(size_t)(o + 3) * HID + w];
  *(float4*)&out0[(size_t)b * OUT + o] = r;
}

extern "C" void kernel_launch(void* const* d_in, const int* in_sizes, int n_in,
                              void* d_out, int out_size, void* d_ws, size_t ws_size,
                              hipStream_t stream) {
  const float* X = (const float*)d_in[0];
  const float* W = (const float*)d_in[1];  // kohonen [HID][KDIM]
  const float* G = (const float*)d_in[2];  // grossberg [OUT][HID]
  float* out0 = (float*)d_out;                  // [BATCH][OUT] f32
  float* out_idx = out0 + (size_t)BATCH * OUT;  // [BATCH] f32 indices

  char* ws = (char*)d_ws;
  float* w2 = (float*)ws;                       // 16 KB
  int* win = (int*)(ws + 16384);                // 32 KB
  float4* partials = (float4*)(ws + 65536);     // 8192*64*16 = 8 MB
  ushort* xh = (ushort*)(ws + 65536 + 8388608);
  ushort* xl = xh + (size_t)BATCH * KDIM;       // 8 MB each
  ushort* wh = xl + (size_t)BATCH * KDIM;
  ushort* wl = wh + (size_t)HID * KDIM;         // 4 MB each

  split_kernel<<<4096, 256, 0, stream>>>(X, xh, xl, BATCH * KDIM / 4);
  split_kernel<<<2048, 256, 0, stream>>>(W, wh, wl, HID * KDIM / 4);
  w2_kernel<<<HID, 64, 0, stream>>>(W, w2);
  mfma_dist_kernel<<<2048, 256, 0, stream>>>(xh, xl, wh, wl, w2, partials);
  recheck_kernel<<<BATCH / 4, 256, 0, stream>>>(X, W, partials, win, out_idx);
  gather_kernel<<<BATCH, 256, 0, stream>>>(G, win, out0);
}

// Round 6
// 812.639 us; speedup vs baseline: 1.1145x; 1.1145x over previous
//
#include <hip/hip_runtime.h>
#include <hip/hip_bf16.h>

#define BATCH 8192
#define HID   4096
#define KDIM  512
#define OUT   1024

#define BM 128
#define BN 128
#define BK 32
#define NKSTEP (KDIM / BK)   // 16
#define NCH 64               // HID / 64 partial chunks per row

typedef __attribute__((ext_vector_type(8))) short bf16x8;
typedef __attribute__((ext_vector_type(4))) float f32x4;

__device__ __forceinline__ ushort bf16_rne(float x) {
  unsigned u = __float_as_uint(x);
  unsigned r = u + 0x7fffu + ((u >> 16) & 1u);
  return (ushort)(r >> 16);
}

__device__ __forceinline__ void gld_lds16(const ushort* g, ushort* l) {
  // 16B per lane: LDS dest = uniform base + lane*16 (linear fill)
  __builtin_amdgcn_global_load_lds(
      (const __attribute__((address_space(1))) unsigned int*)g,
      (__attribute__((address_space(3))) unsigned int*)l, 16, 0, 0);
}

__device__ __forceinline__ void top2_upd(float v, int idx, float& v1, int& i1,
                                         float& v2, int& i2) {
  if (v < v1 || (v == v1 && idx < i1)) { v2 = v1; i2 = i1; v1 = v; i1 = idx; }
  else if (v < v2 || (v == v2 && idx < i2)) { v2 = v; i2 = idx; }
}

__device__ __forceinline__ void top3_upd(float v, int idx,
    float& v1, int& i1, float& v2, int& i2, float& v3, int& i3) {
  if (v < v1 || (v == v1 && idx < i1)) { v3 = v2; i3 = i2; v2 = v1; i2 = i1; v1 = v; i1 = idx; }
  else if (v < v2 || (v == v2 && idx < i2)) { v3 = v2; i3 = i2; v2 = v; i2 = idx; }
  else if (v < v3 || (v == v3 && idx < i3)) { v3 = v; i3 = idx; }
}

// ---- split f32 -> bf16 hi + bf16 lo (x = hi + lo + O(2^-17 x)) --------------
__global__ void __launch_bounds__(256)
split_kernel(const float* __restrict__ src, ushort* __restrict__ hi,
             ushort* __restrict__ lo, int n4) {
  int i = blockIdx.x * 256 + threadIdx.x;
  if (i >= n4) return;
  float4 v = ((const float4*)src)[i];
  ushort4 h, l;
  float f;
  h.x = bf16_rne(v.x); f = __uint_as_float((unsigned)h.x << 16); l.x = bf16_rne(v.x - f);
  h.y = bf16_rne(v.y); f = __uint_as_float((unsigned)h.y << 16); l.y = bf16_rne(v.y - f);
  h.z = bf16_rne(v.z); f = __uint_as_float((unsigned)h.z << 16); l.z = bf16_rne(v.z - f);
  h.w = bf16_rne(v.w); f = __uint_as_float((unsigned)h.w << 16); l.w = bf16_rne(v.w - f);
  ((ushort4*)hi)[i] = h;
  ((ushort4*)lo)[i] = l;
}

// ---------------- w2[j] = sum_k W[j,k]^2 (f32, approx pass only) -------------
__global__ void __launch_bounds__(64)
w2_kernel(const float* __restrict__ W, float* __restrict__ w2) {
  int j = blockIdx.x, lane = threadIdx.x;
  const float4* row = (const float4*)(W + (size_t)j * KDIM);
  float s = 0.f;
#pragma unroll
  for (int i = 0; i < 2; ++i) {
    float4 v = row[lane + i * 64];
    s += v.x * v.x + v.y * v.y + v.z * v.z + v.w * v.w;
  }
#pragma unroll
  for (int off = 32; off; off >>= 1) s += __shfl_down(s, off);
  if (lane == 0) w2[j] = s;
}

// ------ split-bf16 MFMA GEMM (dot = XhWh + XlWh + XhWl) + fused top-2 --------
// 128x128 tile, 4 waves (2x2), 64x64/wave, 16x16x32 MFMA, BK=32, single-buffer
// LDS (m97 structure). Staging via global_load_lds: wave w DMA-fills buffer w
// (xh|xl|wh|wl, 8KB) linearly; unit u = kb*128 + row, src = (tile0+row)*K+kb*8.
__global__ void __launch_bounds__(256, 2)
mfma_dist_kernel(const ushort* __restrict__ xh, const ushort* __restrict__ xl,
                 const ushort* __restrict__ wh, const ushort* __restrict__ wl,
                 const float* __restrict__ w2, float4* __restrict__ partials) {
  __shared__ ushort smem[4 * 4096];   // xh|xl|wh|wl, 8KB each

  const int tid = threadIdx.x;
  // bijective XCD swizzle (nwg=2048, 2048%8==0)
  const int wg = (int)blockIdx.x;
  const int swz = (wg & 7) * 256 + (wg >> 3);
  const int rb = swz >> 5;            // 64 row-blocks
  const int cb = swz & 31;            // 32 col-blocks
  const int row0 = rb * BM;
  const int col0 = cb * BN;

  const int lane = tid & 63;
  const int wid = __builtin_amdgcn_readfirstlane(tid >> 6);
  const int wr = wid >> 1, wc = wid & 1;
  const int lr = lane & 15, lg = lane >> 4;

  // staging source base for this wave's buffer (wid: 0=xh 1=xl 2=wh 3=wl)
  const ushort* sbase = (wid & 2) ? ((wid & 1) ? wl : wh) : ((wid & 1) ? xl : xh);
  sbase += (size_t)((wid & 2) ? col0 : row0) * KDIM;
  ushort* lbase = &smem[wid * 4096];

  f32x4 acc[4][4];
#pragma unroll
  for (int mi = 0; mi < 4; ++mi)
#pragma unroll
    for (int ni = 0; ni < 4; ++ni) acc[mi][ni] = (f32x4){0.f, 0.f, 0.f, 0.f};

  const int abase = (lg * 128 + wr * 64 + lr) * 8;   // ushort idx into xh seg
  const int bbase = (lg * 128 + wc * 64 + lr) * 8;   // ushort idx into wh seg

  for (int step = 0; step < NKSTEP; ++step) {
    // ---- stage this K-step: 8 x 16B-per-lane DMA per wave -------------------
    const ushort* sk = sbase + step * BK;
#pragma unroll
    for (int q = 0; q < 8; ++q) {
      const int row = ((q & 1) * 64) + lane;
      const int kb = q >> 1;
      gld_lds16(sk + (size_t)row * KDIM + kb * 8, lbase + q * 512);
    }
    __syncthreads();   // drains vmcnt(0): DMA complete, visible to all

    bf16x8 af[4], al[4], bfr[4];
#pragma unroll
    for (int mi = 0; mi < 4; ++mi) af[mi] = *(const bf16x8*)&smem[abase + mi * 128];
#pragma unroll
    for (int mi = 0; mi < 4; ++mi) al[mi] = *(const bf16x8*)&smem[4096 + abase + mi * 128];
#pragma unroll
    for (int ni = 0; ni < 4; ++ni) bfr[ni] = *(const bf16x8*)&smem[8192 + bbase + ni * 128];
#pragma unroll
    for (int mi = 0; mi < 4; ++mi)
#pragma unroll
      for (int ni = 0; ni < 4; ++ni)
        acc[mi][ni] = __builtin_amdgcn_mfma_f32_16x16x32_bf16(af[mi], bfr[ni], acc[mi][ni], 0, 0, 0);
#pragma unroll
    for (int mi = 0; mi < 4; ++mi)
#pragma unroll
      for (int ni = 0; ni < 4; ++ni)
        acc[mi][ni] = __builtin_amdgcn_mfma_f32_16x16x32_bf16(al[mi], bfr[ni], acc[mi][ni], 0, 0, 0);
#pragma unroll
    for (int ni = 0; ni < 4; ++ni) bfr[ni] = *(const bf16x8*)&smem[12288 + bbase + ni * 128];
#pragma unroll
    for (int mi = 0; mi < 4; ++mi)
#pragma unroll
      for (int ni = 0; ni < 4; ++ni)
        acc[mi][ni] = __builtin_amdgcn_mfma_f32_16x16x32_bf16(af[mi], bfr[ni], acc[mi][ni], 0, 0, 0);
    __syncthreads();   // frag reads done before next DMA overwrite
  }

  // ---- epilogue: v = w2[col] - 2*dot ; per-row top-2 over this 64-col chunk
  float w2v[4];
#pragma unroll
  for (int ni = 0; ni < 4; ++ni) w2v[ni] = w2[col0 + wc * 64 + ni * 16 + lr];

  float v1[4][4], v2[4][4];
  int i1[4][4], i2[4][4];
#pragma unroll
  for (int mi = 0; mi < 4; ++mi)
#pragma unroll
    for (int rg = 0; rg < 4; ++rg) {
      v1[mi][rg] = 3.4e38f; v2[mi][rg] = 3.4e38f;
      i1[mi][rg] = 0x7fffffff; i2[mi][rg] = 0x7fffffff;
    }
#pragma unroll
  for (int mi = 0; mi < 4; ++mi)
#pragma unroll
    for (int ni = 0; ni < 4; ++ni) {
      const int col = col0 + wc * 64 + ni * 16 + lr;
#pragma unroll
      for (int rg = 0; rg < 4; ++rg) {
        float v = fmaf(-2.f, acc[mi][ni][rg], w2v[ni]);
        top2_upd(v, col, v1[mi][rg], i1[mi][rg], v2[mi][rg], i2[mi][rg]);
      }
    }
#pragma unroll
  for (int m = 1; m < 16; m <<= 1) {
#pragma unroll
    for (int mi = 0; mi < 4; ++mi)
#pragma unroll
      for (int rg = 0; rg < 4; ++rg) {
        float ov1 = __shfl_xor(v1[mi][rg], m);
        int oi1 = __shfl_xor(i1[mi][rg], m);
        float ov2 = __shfl_xor(v2[mi][rg], m);
        int oi2 = __shfl_xor(i2[mi][rg], m);
        top2_upd(ov1, oi1, v1[mi][rg], i1[mi][rg], v2[mi][rg], i2[mi][rg]);
        top2_upd(ov2, oi2, v1[mi][rg], i1[mi][rg], v2[mi][rg], i2[mi][rg]);
      }
  }
  if (lr == 0) {
    const int chunk = cb * 2 + wc;
#pragma unroll
    for (int mi = 0; mi < 4; ++mi)
#pragma unroll
      for (int rg = 0; rg < 4; ++rg) {
        const int row = row0 + wr * 64 + mi * 16 + lg * 4 + rg;
        partials[(size_t)row * NCH + chunk] =
            make_float4(v1[mi][rg], v2[mi][rg],
                        __int_as_float(i1[mi][rg]), __int_as_float(i2[mi][rg]));
      }
  }
}

// ------- merge 64 chunk partials; fp64 recheck top-3; emit winner ------------
__global__ void __launch_bounds__(256)
recheck_kernel(const float* __restrict__ X, const float* __restrict__ W,
               const float4* __restrict__ partials, int* __restrict__ win,
               float* __restrict__ out_idx) {
  int lane = threadIdx.x & 63;
  int b = blockIdx.x * 4 + (threadIdx.x >> 6);
  float v1 = 3.4e38f, v2 = 3.4e38f, v3 = 3.4e38f;
  int i1 = 0x7fffffff, i2 = 0x7fffffff, i3 = 0x7fffffff;
  for (int c = 0; c < NCH; ++c) {
    float4 p = partials[(size_t)b * NCH + c];
    top3_upd(p.x, __float_as_int(p.z), v1, i1, v2, i2, v3, i3);
    top3_upd(p.y, __float_as_int(p.w), v1, i1, v2, i2, v3, i3);
  }
  const float* xr = X + (size_t)b * KDIM;
  const float* w1 = W + (size_t)i1 * KDIM;
  const float* w2p = W + (size_t)i2 * KDIM;
  const float* w3 = W + (size_t)i3 * KDIM;
  double s1 = 0.0, s2 = 0.0, s3 = 0.0;
#pragma unroll
  for (int i = 0; i < KDIM / 64; ++i) {
    int k = lane + i * 64;
    double xv = (double)xr[k];
    double d1 = xv - (double)w1[k];
    double d2 = xv - (double)w2p[k];
    double d3 = xv - (double)w3[k];
    s1 += d1 * d1; s2 += d2 * d2; s3 += d3 * d3;
  }
#pragma unroll
  for (int off = 32; off; off >>= 1) {
    s1 += __shfl_down(s1, off);
    s2 += __shfl_down(s2, off);
    s3 += __shfl_down(s3, off);
  }
  if (lane == 0) {
    int wi = i1; double sb = s1;
    if (s2 < sb || (s2 == sb && i2 < wi)) { sb = s2; wi = i2; }
    if (s3 < sb || (s3 == sb && i3 < wi)) { sb = s3; wi = i3; }
    win[b] = wi;
    out_idx[b] = (float)wi;
  }
}

// --------- G^T: GT[h][o] = G[o][h]  (32x32 LDS tiles, +1 pad) ----------------
__global__ void __launch_bounds__(256)
transpose_g_kernel(const float* __restrict__ G, float* __restrict__ GT) {
  __shared__ float tile[32][33];
  const int tx = threadIdx.x & 31, ty = threadIdx.x >> 5;
  const int o0 = blockIdx.x * 32, h0 = blockIdx.y * 32;
#pragma unroll
  for (int i = 0; i < 32; i += 8)
    tile[ty + i][tx] = G[(size_t)(o0 + ty + i) * HID + h0 + tx];
  __syncthreads();
#pragma unroll
  for (int i = 0; i < 32; i += 8)
    GT[(size_t)(h0 + ty + i) * OUT + o0 + tx] = tile[tx][ty + i];
}

// --------- out0[b,:] = GT[win[b], :]  (contiguous 4KB row copy) --------------
__global__ void __launch_bounds__(256)
gather_fast_kernel(const float* __restrict__ GT, const int* __restrict__ win,
                   float* __restrict__ out0) {
  int b = blockIdx.x;
  int w = win[b];
  w = (w < 0) ? 0 : (w > HID - 1 ? HID - 1 : w);
  float4 v = ((const float4*)(GT + (size_t)w * OUT))[threadIdx.x];
  ((float4*)(out0 + (size_t)b * OUT))[threadIdx.x] = v;
}

// --------- fallback: strided gather straight from G --------------------------
__global__ void __launch_bounds__(256)
gather_kernel(const float* __restrict__ G, const int* __restrict__ win,
              float* __restrict__ out0) {
  int b = blockIdx.x;
  int w = win[b];
  w = (w < 0) ? 0 : (w > HID - 1 ? HID - 1 : w);
  int o = threadIdx.x * 4;
  float4 r;
  r.x = G[(size_t)(o + 0) * HID + w];
  r.y = G[(size_t)(o + 1) * HID + w];
  r.z = G[(size_t)(o + 2) * HID + w];
  r.w = G[(size_t)(o + 3) * HID + w];
  *(float4*)&out0[(size_t)b * OUT + o] = r;
}

extern "C" void kernel_launch(void* const* d_in, const int* in_sizes, int n_in,
                              void* d_out, int out_size, void* d_ws, size_t ws_size,
                              hipStream_t stream) {
  const float* X = (const float*)d_in[0];
  const float* W = (const float*)d_in[1];  // kohonen [HID][KDIM]
  const float* G = (const float*)d_in[2];  // grossberg [OUT][HID]
  float* out0 = (float*)d_out;                  // [BATCH][OUT] f32
  float* out_idx = out0 + (size_t)BATCH * OUT;  // [BATCH] f32 indices

  char* ws = (char*)d_ws;
  float* w2 = (float*)ws;                       // 16 KB
  int* win = (int*)(ws + 16384);                // 32 KB
  float4* partials = (float4*)(ws + 65536);     // 8 MB
  ushort* xh = (ushort*)(ws + 65536 + 8388608);
  ushort* xl = xh + (size_t)BATCH * KDIM;       // 8 MB each
  ushort* wh = xl + (size_t)BATCH * KDIM;
  ushort* wl = wh + (size_t)HID * KDIM;         // 4 MB each
  float* GT = (float*)(ws + 33619968);          // 16 MB
  const bool use_gt = ws_size >= (size_t)33619968 + 16777216;

  split_kernel<<<4096, 256, 0, stream>>>(X, xh, xl, BATCH * KDIM / 4);
  split_kernel<<<2048, 256, 0, stream>>>(W, wh, wl, HID * KDIM / 4);
  w2_kernel<<<HID, 64, 0, stream>>>(W, w2);
  if (use_gt)
    transpose_g_kernel<<<dim3(OUT / 32, HID / 32), 256, 0, stream>>>(G, GT);
  mfma_dist_kernel<<<2048, 256, 0, stream>>>(xh, xl, wh, wl, w2, partials);
  recheck_kernel<<<BATCH / 4, 256, 0, stream>>>(X, W, partials, win, out_idx);
  if (use_gt)
    gather_fast_kernel<<<BATCH, 256, 0, stream>>>(GT, win, out0);
  else
    gather_kernel<<<BATCH, 256, 0, stream>>>(G, win, out0);
}

// Round 9
// 641.185 us; speedup vs baseline: 1.4126x; 1.2674x over previous
//
#include <hip/hip_runtime.h>
#include <hip/hip_bf16.h>

#define BATCH 8192
#define HID   4096
#define KDIM  512
#define OUT   1024

#define BM 128
#define BN 128
#define BK 32
#define NKSTEP (KDIM / BK)   // 16
#define NCH 64               // HID / 64 partial chunks per row
#define TILE_UNITS (NKSTEP * 512)   // 16B units per 128-row tile (8192)

typedef __attribute__((ext_vector_type(8))) short bf16x8;
typedef __attribute__((ext_vector_type(4))) float f32x4;

__device__ __forceinline__ ushort bf16_rne(float x) {
  unsigned u = __float_as_uint(x);
  unsigned r = u + 0x7fffu + ((u >> 16) & 1u);
  return (ushort)(r >> 16);
}

__device__ __forceinline__ void gld_lds16(const ushort* g, ushort* l) {
  // 16B per lane: LDS dest = wave-uniform base + lane*16 (linear fill)
  __builtin_amdgcn_global_load_lds(
      (const __attribute__((address_space(1))) unsigned int*)g,
      (__attribute__((address_space(3))) unsigned int*)l, 16, 0, 0);
}

__device__ __forceinline__ void top2_upd(float v, int idx, float& v1, int& i1,
                                         float& v2, int& i2) {
  if (v < v1 || (v == v1 && idx < i1)) { v2 = v1; i2 = i1; v1 = v; i1 = idx; }
  else if (v < v2 || (v == v2 && idx < i2)) { v2 = v; i2 = idx; }
}

__device__ __forceinline__ void top3_upd(float v, int idx,
    float& v1, int& i1, float& v2, int& i2, float& v3, int& i3) {
  if (v < v1 || (v == v1 && idx < i1)) { v3 = v2; i3 = i2; v2 = v1; i2 = i1; v1 = v; i1 = idx; }
  else if (v < v2 || (v == v2 && idx < i2)) { v3 = v2; i3 = i2; v2 = v; i2 = idx; }
  else if (v < v3 || (v == v3 && idx < i3)) { v3 = v; i3 = idx; }
}

// ---- split f32 -> bf16 hi+lo, written in TILED layout ----------------------
// unit u (16B = 8 bf16): row = u&127, kb = (u>>7)&3, step = (u>>9)&15, tb = u>>13
// holds src[(tb*128+row)*KDIM + step*32 + kb*8 .. +8]. DMA in mfma_dist reads
// units sequentially -> fully coalesced 1KB per global_load_lds call.
__global__ void __launch_bounds__(256)
split_tile_kernel(const float* __restrict__ src, uint4* __restrict__ dH,
                  uint4* __restrict__ dL) {
  const int u = blockIdx.x * 256 + threadIdx.x;
  const int row = u & 127, kb = (u >> 7) & 3, step = (u >> 9) & 15, tb = u >> 13;
  const float* s = src + (size_t)(tb * 128 + row) * KDIM + step * 32 + kb * 8;
  float4 p0 = *(const float4*)s;
  float4 p1 = *(const float4*)(s + 4);
  float x[8] = {p0.x, p0.y, p0.z, p0.w, p1.x, p1.y, p1.z, p1.w};
  unsigned h[8], l[8];
#pragma unroll
  for (int i = 0; i < 8; ++i) {
    h[i] = bf16_rne(x[i]);
    float f = __uint_as_float(h[i] << 16);
    l[i] = bf16_rne(x[i] - f);
  }
  dH[u] = make_uint4(h[0] | (h[1] << 16), h[2] | (h[3] << 16),
                     h[4] | (h[5] << 16), h[6] | (h[7] << 16));
  dL[u] = make_uint4(l[0] | (l[1] << 16), l[2] | (l[3] << 16),
                     l[4] | (l[5] << 16), l[6] | (l[7] << 16));
}

// ---------------- w2[j] = sum_k W[j,k]^2 (f32, approx pass only) -------------
__global__ void __launch_bounds__(64)
w2_kernel(const float* __restrict__ W, float* __restrict__ w2) {
  int j = blockIdx.x, lane = threadIdx.x;
  const float4* row = (const float4*)(W + (size_t)j * KDIM);
  float s = 0.f;
#pragma unroll
  for (int i = 0; i < 2; ++i) {
    float4 v = row[lane + i * 64];
    s += v.x * v.x + v.y * v.y + v.z * v.z + v.w * v.w;
  }
#pragma unroll
  for (int off = 32; off; off >>= 1) s += __shfl_down(s, off);
  if (lane == 0) w2[j] = s;
}

// ------ split-bf16 MFMA GEMM (dot = XhWh + XlWh + XhWl) + fused top-2 --------
// 128x128 tile, 4 waves (2x2), 64x64/wave, 16x16x32 MFMA, BK=32, single-buffer
// LDS (m97 structure). Wave w DMA-fills its buffer (xh|xl|wh|wl segment, 8KB)
// from the TILED arrays: 8 x 1KB contiguous global_load_lds per K-step.
__global__ void __launch_bounds__(256)
mfma_dist_kernel(const ushort* __restrict__ xhT, const ushort* __restrict__ xlT,
                 const ushort* __restrict__ whT, const ushort* __restrict__ wlT,
                 const float* __restrict__ w2, float4* __restrict__ partials) {
  __shared__ ushort smem[4 * 4096];   // xh|xl|wh|wl, 8KB each

  const int tid = threadIdx.x;
  // bijective XCD swizzle (nwg=2048, 2048%8==0)
  const int wg = (int)blockIdx.x;
  const int swz = (wg & 7) * 256 + (wg >> 3);
  const int rb = swz >> 5;            // 64 row-blocks
  const int cb = swz & 31;            // 32 col-blocks
  const int row0 = rb * BM;
  const int col0 = cb * BN;

  const int lane = tid & 63;
  const int wid = __builtin_amdgcn_readfirstlane(tid >> 6);
  const int wr = wid >> 1, wc = wid & 1;
  const int lr = lane & 15, lg = lane >> 4;

  // staging source: this wave's tiled array (wid: 0=xh 1=xl 2=wh 3=wl)
  const ushort* sbase = (wid & 2) ? ((wid & 1) ? wlT : whT) : ((wid & 1) ? xlT : xhT);
  sbase += (size_t)((wid & 2) ? cb : rb) * (TILE_UNITS * 8);
  ushort* lbase = &smem[wid * 4096];

  f32x4 acc[4][4];
#pragma unroll
  for (int mi = 0; mi < 4; ++mi)
#pragma unroll
    for (int ni = 0; ni < 4; ++ni) acc[mi][ni] = (f32x4){0.f, 0.f, 0.f, 0.f};

  const int abase = (lg * 128 + wr * 64 + lr) * 8;   // ushort idx into xh seg
  const int bbase = (lg * 128 + wc * 64 + lr) * 8;   // ushort idx into wh seg

  for (int step = 0; step < NKSTEP; ++step) {
    // ---- stage: 8 x (64 lanes x 16B contiguous) = 8KB sequential per wave ---
    const ushort* sk = sbase + (size_t)step * 512 * 8;
#pragma unroll
    for (int q = 0; q < 8; ++q)
      gld_lds16(sk + (q * 64 + lane) * 8, lbase + q * 512);
    __syncthreads();   // drains vmcnt(0): DMA complete, visible to all

    // ---- 3-phase MFMA, peak 12 live fragments (48 VGPR) --------------------
    bf16x8 fa[4], fb[4], ft[4];
#pragma unroll
    for (int mi = 0; mi < 4; ++mi) fa[mi] = *(const bf16x8*)&smem[abase + mi * 128];
#pragma unroll
    for (int ni = 0; ni < 4; ++ni) fb[ni] = *(const bf16x8*)&smem[8192 + bbase + ni * 128];
#pragma unroll
    for (int mi = 0; mi < 4; ++mi)
#pragma unroll
      for (int ni = 0; ni < 4; ++ni)
        acc[mi][ni] = __builtin_amdgcn_mfma_f32_16x16x32_bf16(fa[mi], fb[ni], acc[mi][ni], 0, 0, 0);
#pragma unroll
    for (int mi = 0; mi < 4; ++mi) ft[mi] = *(const bf16x8*)&smem[4096 + abase + mi * 128];
#pragma unroll
    for (int mi = 0; mi < 4; ++mi)
#pragma unroll
      for (int ni = 0; ni < 4; ++ni)
        acc[mi][ni] = __builtin_amdgcn_mfma_f32_16x16x32_bf16(ft[mi], fb[ni], acc[mi][ni], 0, 0, 0);
#pragma unroll
    for (int ni = 0; ni < 4; ++ni) ft[ni] = *(const bf16x8*)&smem[12288 + bbase + ni * 128];
#pragma unroll
    for (int mi = 0; mi < 4; ++mi)
#pragma unroll
      for (int ni = 0; ni < 4; ++ni)
        acc[mi][ni] = __builtin_amdgcn_mfma_f32_16x16x32_bf16(fa[mi], ft[ni], acc[mi][ni], 0, 0, 0);
    __syncthreads();   // frag reads done before next DMA overwrite
  }

  // ---- epilogue: v = w2[col] - 2*dot ; per-mi top-2 fold (low reg pressure)
  float w2v[4];
#pragma unroll
  for (int ni = 0; ni < 4; ++ni) w2v[ni] = w2[col0 + wc * 64 + ni * 16 + lr];
  const int chunk = cb * 2 + wc;

#pragma unroll
  for (int mi = 0; mi < 4; ++mi) {
    float v1[4], v2[4];
    int i1[4], i2[4];
#pragma unroll
    for (int rg = 0; rg < 4; ++rg) {
      v1[rg] = 3.4e38f; v2[rg] = 3.4e38f;
      i1[rg] = 0x7fffffff; i2[rg] = 0x7fffffff;
    }
#pragma unroll
    for (int ni = 0; ni < 4; ++ni) {
      const int col = col0 + wc * 64 + ni * 16 + lr;
#pragma unroll
      for (int rg = 0; rg < 4; ++rg) {
        float v = fmaf(-2.f, acc[mi][ni][rg], w2v[ni]);
        top2_upd(v, col, v1[rg], i1[rg], v2[rg], i2[rg]);
      }
    }
#pragma unroll
    for (int m = 1; m < 16; m <<= 1) {
#pragma unroll
      for (int rg = 0; rg < 4; ++rg) {
        float ov1 = __shfl_xor(v1[rg], m);
        int oi1 = __shfl_xor(i1[rg], m);
        float ov2 = __shfl_xor(v2[rg], m);
        int oi2 = __shfl_xor(i2[rg], m);
        top2_upd(ov1, oi1, v1[rg], i1[rg], v2[rg], i2[rg]);
        top2_upd(ov2, oi2, v1[rg], i1[rg], v2[rg], i2[rg]);
      }
    }
    if (lr == 0) {
#pragma unroll
      for (int rg = 0; rg < 4; ++rg) {
        const int row = row0 + wr * 64 + mi * 16 + lg * 4 + rg;
        partials[(size_t)row * NCH + chunk] =
            make_float4(v1[rg], v2[rg],
                        __int_as_float(i1[rg]), __int_as_float(i2[rg]));
      }
    }
  }
}

// ------- merge 64 chunk partials; fp64 recheck top-3; emit winner ------------
__global__ void __launch_bounds__(256)
recheck_kernel(const float* __restrict__ X, const float* __restrict__ W,
               const float4* __restrict__ partials, int* __restrict__ win,
               float* __restrict__ out_idx) {
  int lane = threadIdx.x & 63;
  int b = blockIdx.x * 4 + (threadIdx.x >> 6);
  float v1 = 3.4e38f, v2 = 3.4e38f, v3 = 3.4e38f;
  int i1 = 0x7fffffff, i2 = 0x7fffffff, i3 = 0x7fffffff;
  for (int c = 0; c < NCH; ++c) {
    float4 p = partials[(size_t)b * NCH + c];
    top3_upd(p.x, __float_as_int(p.z), v1, i1, v2, i2, v3, i3);
    top3_upd(p.y, __float_as_int(p.w), v1, i1, v2, i2, v3, i3);
  }
  const float* xr = X + (size_t)b * KDIM;
  const float* w1 = W + (size_t)i1 * KDIM;
  const float* w2p = W + (size_t)i2 * KDIM;
  const float* w3 = W + (size_t)i3 * KDIM;
  double s1 = 0.0, s2 = 0.0, s3 = 0.0;
#pragma unroll
  for (int i = 0; i < KDIM / 64; ++i) {
    int k = lane + i * 64;
    double xv = (double)xr[k];
    double d1 = xv - (double)w1[k];
    double d2 = xv - (double)w2p[k];
    double d3 = xv - (double)w3[k];
    s1 += d1 * d1; s2 += d2 * d2; s3 += d3 * d3;
  }
#pragma unroll
  for (int off = 32; off; off >>= 1) {
    s1 += __shfl_down(s1, off);
    s2 += __shfl_down(s2, off);
    s3 += __shfl_down(s3, off);
  }
  if (lane == 0) {
    int wi = i1; double sb = s1;
    if (s2 < sb || (s2 == sb && i2 < wi)) { sb = s2; wi = i2; }
    if (s3 < sb || (s3 == sb && i3 < wi)) { sb = s3; wi = i3; }
    win[b] = wi;
    out_idx[b] = (float)wi;
  }
}

// --------- G^T: GT[h][o] = G[o][h]  (32x32 LDS tiles, +1 pad) ----------------
__global__ void __launch_bounds__(256)
transpose_g_kernel(const float* __restrict__ G, float* __restrict__ GT) {
  __shared__ float tile[32][33];
  const int tx = threadIdx.x & 31, ty = threadIdx.x >> 5;
  const int o0 = blockIdx.x * 32, h0 = blockIdx.y * 32;
#pragma unroll
  for (int i = 0; i < 32; i += 8)
    tile[ty + i][tx] = G[(size_t)(o0 + ty + i) * HID + h0 + tx];
  __syncthreads();
#pragma unroll
  for (int i = 0; i < 32; i += 8)
    GT[(size_t)(h0 + ty + i) * OUT + o0 + tx] = tile[tx][ty + i];
}

// --------- out0[b,:] = GT[win[b], :]  (contiguous 4KB row copy) --------------
__global__ void __launch_bounds__(256)
gather_fast_kernel(const float* __restrict__ GT, const int* __restrict__ win,
                   float* __restrict__ out0) {
  int b = blockIdx.x;
  int w = win[b];
  w = (w < 0) ? 0 : (w > HID - 1 ? HID - 1 : w);
  float4 v = ((const float4*)(GT + (size_t)w * OUT))[threadIdx.x];
  ((float4*)(out0 + (size_t)b * OUT))[threadIdx.x] = v;
}

// --------- fallback: strided gather straight from G --------------------------
__global__ void __launch_bounds__(256)
gather_kernel(const float* __restrict__ G, const int* __restrict__ win,
              float* __restrict__ out0) {
  int b = blockIdx.x;
  int w = win[b];
  w = (w < 0) ? 0 : (w > HID - 1 ? HID - 1 : w);
  int o = threadIdx.x * 4;
  float4 r;
  r.x = G[(size_t)(o + 0) * HID + w];
  r.y = G[(size_t)(o + 1) * HID + w];
  r.z = G[(size_t)(o + 2) * HID + w];
  r.w = G[(size_t)(o + 3) * HID + w];
  *(float4*)&out0[(size_t)b * OUT + o] = r;
}

extern "C" void kernel_launch(void* const* d_in, const int* in_sizes, int n_in,
                              void* d_out, int out_size, void* d_ws, size_t ws_size,
                              hipStream_t stream) {
  const float* X = (const float*)d_in[0];
  const float* W = (const float*)d_in[1];  // kohonen [HID][KDIM]
  const float* G = (const float*)d_in[2];  // grossberg [OUT][HID]
  float* out0 = (float*)d_out;                  // [BATCH][OUT] f32
  float* out_idx = out0 + (size_t)BATCH * OUT;  // [BATCH] f32 indices

  char* ws = (char*)d_ws;
  float* w2 = (float*)ws;                       // 16 KB
  int* win = (int*)(ws + 16384);                // 32 KB
  float4* partials = (float4*)(ws + 65536);     // 8 MB
  ushort* xh = (ushort*)(ws + 65536 + 8388608); // tiled, 8 MB
  ushort* xl = xh + (size_t)BATCH * KDIM;       // tiled, 8 MB
  ushort* wh = xl + (size_t)BATCH * KDIM;       // tiled, 4 MB
  ushort* wl = wh + (size_t)HID * KDIM;         // tiled, 4 MB
  float* GT = (float*)(ws + 33619968);          // 16 MB
  const bool use_gt = ws_size >= (size_t)33619968 + 16777216;

  split_tile_kernel<<<BATCH * KDIM / 8 / 256, 256, 0, stream>>>(X, (uint4*)xh, (uint4*)xl);
  split_tile_kernel<<<HID * KDIM / 8 / 256, 256, 0, stream>>>(W, (uint4*)wh, (uint4*)wl);
  w2_kernel<<<HID, 64, 0, stream>>>(W, w2);
  if (use_gt)
    transpose_g_kernel<<<dim3(OUT / 32, HID / 32), 256, 0, stream>>>(G, GT);
  mfma_dist_kernel<<<2048, 256, 0, stream>>>(xh, xl, wh, wl, w2, partials);
  recheck_kernel<<<BATCH / 4, 256, 0, stream>>>(X, W, partials, win, out_idx);
  if (use_gt)
    gather_fast_kernel<<<BATCH, 256, 0, stream>>>(GT, win, out0);
  else
    gather_kernel<<<BATCH, 256, 0, stream>>>(G, win, out0);
}

// Round 10
// 637.638 us; speedup vs baseline: 1.4204x; 1.0056x over previous
//
#include <hip/hip_runtime.h>
#include <hip/hip_bf16.h>

#define BATCH 8192
#define HID   4096
#define KDIM  512
#define OUT   1024

#define BM 128
#define BN 128
#define BK 32
#define NKSTEP (KDIM / BK)   // 16
#define NCH 64               // HID / 64 partial chunks per row
#define TILE_UNITS (NKSTEP * 512)   // 16B units per 128-row tile (8192)

typedef __attribute__((ext_vector_type(8))) short bf16x8;
typedef __attribute__((ext_vector_type(4))) float f32x4;

__device__ __forceinline__ ushort bf16_rne(float x) {
  unsigned u = __float_as_uint(x);
  unsigned r = u + 0x7fffu + ((u >> 16) & 1u);
  return (ushort)(r >> 16);
}

__device__ __forceinline__ void gld_lds16(const ushort* g, ushort* l) {
  // 16B per lane: LDS dest = wave-uniform base + lane*16 (linear fill)
  __builtin_amdgcn_global_load_lds(
      (const __attribute__((address_space(1))) unsigned int*)g,
      (__attribute__((address_space(3))) unsigned int*)l, 16, 0, 0);
}

__device__ __forceinline__ void top2_upd(float v, int idx, float& v1, int& i1,
                                         float& v2, int& i2) {
  if (v < v1 || (v == v1 && idx < i1)) { v2 = v1; i2 = i1; v1 = v; i1 = idx; }
  else if (v < v2 || (v == v2 && idx < i2)) { v2 = v; i2 = idx; }
}

__device__ __forceinline__ void top3_upd(float v, int idx,
    float& v1, int& i1, float& v2, int& i2, float& v3, int& i3) {
  if (v < v1 || (v == v1 && idx < i1)) { v3 = v2; i3 = i2; v2 = v1; i2 = i1; v1 = v; i1 = idx; }
  else if (v < v2 || (v == v2 && idx < i2)) { v3 = v2; i3 = i2; v2 = v; i2 = idx; }
  else if (v < v3 || (v == v3 && idx < i3)) { v3 = v; i3 = idx; }
}

// ---- split f32 -> bf16 hi+lo, written in TILED layout ----------------------
// unit u (16B = 8 bf16): row = u&127, kb = (u>>7)&3, step = (u>>9)&15, tb = u>>13
// holds src[(tb*128+row)*KDIM + step*32 + kb*8 .. +8]. DMA in mfma_dist reads
// units sequentially -> fully coalesced 1KB per global_load_lds call.
__global__ void __launch_bounds__(256)
split_tile_kernel(const float* __restrict__ src, uint4* __restrict__ dH,
                  uint4* __restrict__ dL) {
  const int u = blockIdx.x * 256 + threadIdx.x;
  const int row = u & 127, kb = (u >> 7) & 3, step = (u >> 9) & 15, tb = u >> 13;
  const float* s = src + (size_t)(tb * 128 + row) * KDIM + step * 32 + kb * 8;
  float4 p0 = *(const float4*)s;
  float4 p1 = *(const float4*)(s + 4);
  float x[8] = {p0.x, p0.y, p0.z, p0.w, p1.x, p1.y, p1.z, p1.w};
  unsigned h[8], l[8];
#pragma unroll
  for (int i = 0; i < 8; ++i) {
    h[i] = bf16_rne(x[i]);
    float f = __uint_as_float(h[i] << 16);
    l[i] = bf16_rne(x[i] - f);
  }
  dH[u] = make_uint4(h[0] | (h[1] << 16), h[2] | (h[3] << 16),
                     h[4] | (h[5] << 16), h[6] | (h[7] << 16));
  dL[u] = make_uint4(l[0] | (l[1] << 16), l[2] | (l[3] << 16),
                     l[4] | (l[5] << 16), l[6] | (l[7] << 16));
}

// ---------------- w2[j] = sum_k W[j,k]^2 (f32, approx pass only) -------------
__global__ void __launch_bounds__(64)
w2_kernel(const float* __restrict__ W, float* __restrict__ w2) {
  int j = blockIdx.x, lane = threadIdx.x;
  const float4* row = (const float4*)(W + (size_t)j * KDIM);
  float s = 0.f;
#pragma unroll
  for (int i = 0; i < 2; ++i) {
    float4 v = row[lane + i * 64];
    s += v.x * v.x + v.y * v.y + v.z * v.z + v.w * v.w;
  }
#pragma unroll
  for (int off = 32; off; off >>= 1) s += __shfl_down(s, off);
  if (lane == 0) w2[j] = s;
}

// ------ split-bf16 MFMA GEMM (dot = XhWh + XlWh + XhWl) + fused top-2 --------
// 128x128 tile, 4 waves (2x2), 64x64/wave, 16x16x32 MFMA, BK=32.
// 2-PHASE DOUBLE-BUFFERED: per K-step, issue next step's 8 DMAs into buf^1
// FIRST, then ds_read+MFMA from buf, then one __syncthreads() (implicit
// vmcnt(0) drains prefetch that flew under the compute). T3-minimum recipe.
__global__ void __launch_bounds__(256)
mfma_dist_kernel(const ushort* __restrict__ xhT, const ushort* __restrict__ xlT,
                 const ushort* __restrict__ whT, const ushort* __restrict__ wlT,
                 const float* __restrict__ w2, float4* __restrict__ partials) {
  __shared__ ushort smem[2][4 * 4096];   // [buf][xh|xl|wh|wl], 32KB per buf

  const int tid = threadIdx.x;
  // bijective XCD swizzle (nwg=2048, 2048%8==0)
  const int wg = (int)blockIdx.x;
  const int swz = (wg & 7) * 256 + (wg >> 3);
  const int rb = swz >> 5;            // 64 row-blocks
  const int cb = swz & 31;            // 32 col-blocks
  const int row0 = rb * BM;
  const int col0 = cb * BN;

  const int lane = tid & 63;
  const int wid = __builtin_amdgcn_readfirstlane(tid >> 6);
  const int wr = wid >> 1, wc = wid & 1;
  const int lr = lane & 15, lg = lane >> 4;

  // staging source: this wave's tiled array (wid: 0=xh 1=xl 2=wh 3=wl)
  const ushort* sbase = (wid & 2) ? ((wid & 1) ? wlT : whT) : ((wid & 1) ? xlT : xhT);
  sbase += (size_t)((wid & 2) ? cb : rb) * (TILE_UNITS * 8);

  f32x4 acc[4][4];
#pragma unroll
  for (int mi = 0; mi < 4; ++mi)
#pragma unroll
    for (int ni = 0; ni < 4; ++ni) acc[mi][ni] = (f32x4){0.f, 0.f, 0.f, 0.f};

  const int abase = (lg * 128 + wr * 64 + lr) * 8;   // ushort idx into xh seg
  const int bbase = (lg * 128 + wc * 64 + lr) * 8;   // ushort idx into wh seg

  // prologue: stage step 0 into buf 0
#pragma unroll
  for (int q = 0; q < 8; ++q)
    gld_lds16(sbase + (q * 64 + lane) * 8, &smem[0][wid * 4096] + q * 512);
  __syncthreads();

  for (int step = 0; step < NKSTEP; ++step) {
    const int cur = step & 1;
    // ---- prefetch next K-step into buf^1 (flies under the compute below) ---
    if (step + 1 < NKSTEP) {
      const ushort* sk = sbase + (size_t)(step + 1) * 4096;
      ushort* lb = &smem[cur ^ 1][wid * 4096];
#pragma unroll
      for (int q = 0; q < 8; ++q)
        gld_lds16(sk + (q * 64 + lane) * 8, lb + q * 512);
    }

    // ---- compute current buffer: 3-phase MFMA, 12 ds_read_b128 -------------
    const ushort* seg = smem[cur];
    bf16x8 fa[4], fb[4], ft[4];
#pragma unroll
    for (int mi = 0; mi < 4; ++mi) fa[mi] = *(const bf16x8*)&seg[abase + mi * 128];
#pragma unroll
    for (int ni = 0; ni < 4; ++ni) fb[ni] = *(const bf16x8*)&seg[8192 + bbase + ni * 128];
#pragma unroll
    for (int mi = 0; mi < 4; ++mi)
#pragma unroll
      for (int ni = 0; ni < 4; ++ni)
        acc[mi][ni] = __builtin_amdgcn_mfma_f32_16x16x32_bf16(fa[mi], fb[ni], acc[mi][ni], 0, 0, 0);
#pragma unroll
    for (int mi = 0; mi < 4; ++mi) ft[mi] = *(const bf16x8*)&seg[4096 + abase + mi * 128];
#pragma unroll
    for (int mi = 0; mi < 4; ++mi)
#pragma unroll
      for (int ni = 0; ni < 4; ++ni)
        acc[mi][ni] = __builtin_amdgcn_mfma_f32_16x16x32_bf16(ft[mi], fb[ni], acc[mi][ni], 0, 0, 0);
#pragma unroll
    for (int ni = 0; ni < 4; ++ni) ft[ni] = *(const bf16x8*)&seg[12288 + bbase + ni * 128];
#pragma unroll
    for (int mi = 0; mi < 4; ++mi)
#pragma unroll
      for (int ni = 0; ni < 4; ++ni)
        acc[mi][ni] = __builtin_amdgcn_mfma_f32_16x16x32_bf16(fa[mi], ft[ni], acc[mi][ni], 0, 0, 0);

    // one barrier per step: drains prefetch DMAs (vmcnt->0) + read fence
    __syncthreads();
  }

  // ---- epilogue: v = w2[col] - 2*dot ; per-mi top-2 fold (low reg pressure)
  float w2v[4];
#pragma unroll
  for (int ni = 0; ni < 4; ++ni) w2v[ni] = w2[col0 + wc * 64 + ni * 16 + lr];
  const int chunk = cb * 2 + wc;

#pragma unroll
  for (int mi = 0; mi < 4; ++mi) {
    float v1[4], v2[4];
    int i1[4], i2[4];
#pragma unroll
    for (int rg = 0; rg < 4; ++rg) {
      v1[rg] = 3.4e38f; v2[rg] = 3.4e38f;
      i1[rg] = 0x7fffffff; i2[rg] = 0x7fffffff;
    }
#pragma unroll
    for (int ni = 0; ni < 4; ++ni) {
      const int col = col0 + wc * 64 + ni * 16 + lr;
#pragma unroll
      for (int rg = 0; rg < 4; ++rg) {
        float v = fmaf(-2.f, acc[mi][ni][rg], w2v[ni]);
        top2_upd(v, col, v1[rg], i1[rg], v2[rg], i2[rg]);
      }
    }
#pragma unroll
    for (int m = 1; m < 16; m <<= 1) {
#pragma unroll
      for (int rg = 0; rg < 4; ++rg) {
        float ov1 = __shfl_xor(v1[rg], m);
        int oi1 = __shfl_xor(i1[rg], m);
        float ov2 = __shfl_xor(v2[rg], m);
        int oi2 = __shfl_xor(i2[rg], m);
        top2_upd(ov1, oi1, v1[rg], i1[rg], v2[rg], i2[rg]);
        top2_upd(ov2, oi2, v1[rg], i1[rg], v2[rg], i2[rg]);
      }
    }
    if (lr == 0) {
#pragma unroll
      for (int rg = 0; rg < 4; ++rg) {
        const int row = row0 + wr * 64 + mi * 16 + lg * 4 + rg;
        partials[(size_t)row * NCH + chunk] =
            make_float4(v1[rg], v2[rg],
                        __int_as_float(i1[rg]), __int_as_float(i2[rg]));
      }
    }
  }
}

// ------- merge 64 chunk partials; fp64 recheck top-3; emit winner ------------
__global__ void __launch_bounds__(256)
recheck_kernel(const float* __restrict__ X, const float* __restrict__ W,
               const float4* __restrict__ partials, int* __restrict__ win,
               float* __restrict__ out_idx) {
  int lane = threadIdx.x & 63;
  int b = blockIdx.x * 4 + (threadIdx.x >> 6);
  float v1 = 3.4e38f, v2 = 3.4e38f, v3 = 3.4e38f;
  int i1 = 0x7fffffff, i2 = 0x7fffffff, i3 = 0x7fffffff;
  for (int c = 0; c < NCH; ++c) {
    float4 p = partials[(size_t)b * NCH + c];
    top3_upd(p.x, __float_as_int(p.z), v1, i1, v2, i2, v3, i3);
    top3_upd(p.y, __float_as_int(p.w), v1, i1, v2, i2, v3, i3);
  }
  const float* xr = X + (size_t)b * KDIM;
  const float* w1 = W + (size_t)i1 * KDIM;
  const float* w2p = W + (size_t)i2 * KDIM;
  const float* w3 = W + (size_t)i3 * KDIM;
  double s1 = 0.0, s2 = 0.0, s3 = 0.0;
#pragma unroll
  for (int i = 0; i < KDIM / 64; ++i) {
    int k = lane + i * 64;
    double xv = (double)xr[k];
    double d1 = xv - (double)w1[k];
    double d2 = xv - (double)w2p[k];
    double d3 = xv - (double)w3[k];
    s1 += d1 * d1; s2 += d2 * d2; s3 += d3 * d3;
  }
#pragma unroll
  for (int off = 32; off; off >>= 1) {
    s1 += __shfl_down(s1, off);
    s2 += __shfl_down(s2, off);
    s3 += __shfl_down(s3, off);
  }
  if (lane == 0) {
    int wi = i1; double sb = s1;
    if (s2 < sb || (s2 == sb && i2 < wi)) { sb = s2; wi = i2; }
    if (s3 < sb || (s3 == sb && i3 < wi)) { sb = s3; wi = i3; }
    win[b] = wi;
    out_idx[b] = (float)wi;
  }
}

// --------- G^T: GT[h][o] = G[o][h]  (32x32 LDS tiles, +1 pad) ----------------
__global__ void __launch_bounds__(256)
transpose_g_kernel(const float* __restrict__ G, float* __restrict__ GT) {
  __shared__ float tile[32][33];
  const int tx = threadIdx.x & 31, ty = threadIdx.x >> 5;
  const int o0 = blockIdx.x * 32, h0 = blockIdx.y * 32;
#pragma unroll
  for (int i = 0; i < 32; i += 8)
    tile[ty + i][tx] = G[(size_t)(o0 + ty + i) * HID + h0 + tx];
  __syncthreads();
#pragma unroll
  for (int i = 0; i < 32; i += 8)
    GT[(size_t)(h0 + ty + i) * OUT + o0 + tx] = tile[tx][ty + i];
}

// --------- out0[b,:] = GT[win[b], :]  (contiguous 4KB row copy) --------------
__global__ void __launch_bounds__(256)
gather_fast_kernel(const float* __restrict__ GT, const int* __restrict__ win,
                   float* __restrict__ out0) {
  int b = blockIdx.x;
  int w = win[b];
  w = (w < 0) ? 0 : (w > HID - 1 ? HID - 1 : w);
  float4 v = ((const float4*)(GT + (size_t)w * OUT))[threadIdx.x];
  ((float4*)(out0 + (size_t)b * OUT))[threadIdx.x] = v;
}

// --------- fallback: strided gather straight from G --------------------------
__global__ void __launch_bounds__(256)
gather_kernel(const float* __restrict__ G, const int* __restrict__ win,
              float* __restrict__ out0) {
  int b = blockIdx.x;
  int w = win[b];
  w = (w < 0) ? 0 : (w > HID - 1 ? HID - 1 : w);
  int o = threadIdx.x * 4;
  float4 r;
  r.x = G[(size_t)(o + 0) * HID + w];
  r.y = G[(size_t)(o + 1) * HID + w];
  r.z = G[(size_t)(o + 2) * HID + w];
  r.w = G[(size_t)(o + 3) * HID + w];
  *(float4*)&out0[(size_t)b * OUT + o] = r;
}

extern "C" void kernel_launch(void* const* d_in, const int* in_sizes, int n_in,
                              void* d_out, int out_size, void* d_ws, size_t ws_size,
                              hipStream_t stream) {
  const float* X = (const float*)d_in[0];
  const float* W = (const float*)d_in[1];  // kohonen [HID][KDIM]
  const float* G = (const float*)d_in[2];  // grossberg [OUT][HID]
  float* out0 = (float*)d_out;                  // [BATCH][OUT] f32
  float* out_idx = out0 + (size_t)BATCH * OUT;  // [BATCH] f32 indices

  char* ws = (char*)d_ws;
  float* w2 = (float*)ws;                       // 16 KB
  int* win = (int*)(ws + 16384);                // 32 KB
  float4* partials = (float4*)(ws + 65536);     // 8 MB
  ushort* xh = (ushort*)(ws + 65536 + 8388608); // tiled, 8 MB
  ushort* xl = xh + (size_t)BATCH * KDIM;       // tiled, 8 MB
  ushort* wh = xl + (size_t)BATCH * KDIM;       // tiled, 4 MB
  ushort* wl = wh + (size_t)HID * KDIM;         // tiled, 4 MB
  float* GT = (float*)(ws + 33619968);          // 16 MB
  const bool use_gt = ws_size >= (size_t)33619968 + 16777216;

  split_tile_kernel<<<BATCH * KDIM / 8 / 256, 256, 0, stream>>>(X, (uint4*)xh, (uint4*)xl);
  split_tile_kernel<<<HID * KDIM / 8 / 256, 256, 0, stream>>>(W, (uint4*)wh, (uint4*)wl);
  w2_kernel<<<HID, 64, 0, stream>>>(W, w2);
  if (use_gt)
    transpose_g_kernel<<<dim3(OUT / 32, HID / 32), 256, 0, stream>>>(G, GT);
  mfma_dist_kernel<<<2048, 256, 0, stream>>>(xh, xl, wh, wl, w2, partials);
  recheck_kernel<<<BATCH / 4, 256, 0, stream>>>(X, W, partials, win, out_idx);
  if (use_gt)
    gather_fast_kernel<<<BATCH, 256, 0, stream>>>(GT, win, out0);
  else
    gather_kernel<<<BATCH, 256, 0, stream>>>(G, win, out0);
}